// Round 4
// baseline (113.993 us; speedup 1.0000x reference)
//
#include <hip/hip_runtime.h>
#include <hip/hip_fp16.h>
#include <math.h>

#define SEQ   4096
#define DIM   128
#define UDIM  64
#define BATCH 4
#define BS    (BATCH*SEQ)
#define NT    (SEQ/64)   // 64 key tiles
#define NSPLIT 6         // 768 blocks = 3072 waves = exactly one resident pass

typedef _Float16 h8 __attribute__((ext_vector_type(8)));
typedef _Float16 h4 __attribute__((ext_vector_type(4)));
typedef _Float16 h2 __attribute__((ext_vector_type(2)));
typedef float    f4 __attribute__((ext_vector_type(4)));

#define MFMA_K32(a,b,c) __builtin_amdgcn_mfma_f32_16x16x32_f16((a),(b),(c),0,0,0)

__device__ __forceinline__ h2 pk2(float a, float b) {
  return __builtin_bit_cast(h2, __builtin_amdgcn_cvt_pkrtz(a, b));
}
__device__ __forceinline__ float fexp2(float x) {
#if __has_builtin(__builtin_amdgcn_exp2f)
  return __builtin_amdgcn_exp2f(x);
#else
  return exp2f(x);
#endif
}

// async global->LDS, 16B per lane; LDS dest = wave-uniform base + lane*16
__device__ __forceinline__ void stage16(const void* g, void* l) {
  __builtin_amdgcn_global_load_lds(
      (const __attribute__((address_space(1))) unsigned int*)g,
      (__attribute__((address_space(3))) unsigned int*)l, 16, 0, 0);
}

#define WT_STRIDE 272   // W^T row stride (136 halves): conflict-free b128
#define KB_STRIDE 144
#define L2E 1.44269504088896f

// Swizzled layouts, contiguous 8KB per 64-key tile (slot*1024B + lane*16B):
//  kswz: slot (mt*2+ks): lane(quad,n) holds K[kb*16+n][ks*32+quad*8..+7]
//  vswz (K32 A-frag layout): slot (hh*4+ut):
//       lane(quad,n) h8 = V^T[16*ut+n][tile*64 + 32*hh + 8*quad + j], j=0..7
// q is stored PRE-SCALED by log2(e) -> scores emerge in log2 domain.

// ---------------- Kernel A: FUSED qkv projection via MFMA ----------------
__global__ __launch_bounds__(256, 2) void proj_mfma(
    const float* __restrict__ x,
    const float* __restrict__ Wq, const float* __restrict__ bq,
    const float* __restrict__ Wk, const float* __restrict__ bk,
    const float* __restrict__ Wv, const float* __restrict__ bv,
    _Float16* __restrict__ qf, _Float16* __restrict__ kswz, _Float16* __restrict__ vswz)
{
  const int tid  = threadIdx.x;
  const int lane = tid & 63, wv = tid >> 6;
  const int n = lane & 15, quad = lane >> 4;
  const int r0 = blockIdx.x * 64;

  __shared__ __align__(16) char wlds[3][UDIM * WT_STRIDE];   // 52224 B
  __shared__ __align__(16) char kbnc[4 * 16 * KB_STRIDE];    //  9216 B

  #pragma unroll
  for (int p = 0; p < 3; ++p) {
    const float* __restrict__ W = (p == 0) ? Wq : ((p == 1) ? Wk : Wv);
    #pragma unroll
    for (int i = 0; i < 8; ++i) {
      const int idx = i*256 + tid;
      const int nn  = idx & 63;
      const int k4  = (idx >> 6) * 4;
      const float w0 = W[(k4+0)*UDIM + nn];
      const float w1 = W[(k4+1)*UDIM + nn];
      const float w2 = W[(k4+2)*UDIM + nn];
      const float w3 = W[(k4+3)*UDIM + nn];
      int2 wd;
      wd.x = __builtin_bit_cast(int, pk2(w0, w1));
      wd.y = __builtin_bit_cast(int, pk2(w2, w3));
      *(int2*)(wlds[p] + nn*WT_STRIDE + k4*2) = wd;
    }
  }

  const int row = r0 + wv*16 + n;
  h8 xa[4];
  #pragma unroll
  for (int ks = 0; ks < 4; ++ks) {
    const float* xp = x + (size_t)row*DIM + ks*32 + quad*8;
    const f4 a = *(const f4*)xp, b = *(const f4*)(xp + 4);
    int4 pkd;
    pkd.x = __builtin_bit_cast(int, pk2(a[0], a[1]));
    pkd.y = __builtin_bit_cast(int, pk2(a[2], a[3]));
    pkd.z = __builtin_bit_cast(int, pk2(b[0], b[1]));
    pkd.w = __builtin_bit_cast(int, pk2(b[2], b[3]));
    xa[ks] = __builtin_bit_cast(h8, pkd);
  }
  __syncthreads();

  const int b  = r0 / SEQ;
  const int kb = ((r0 % SEQ) >> 4) + wv;
  const int vt = (r0 % SEQ) >> 6;          // 64-key tile index within batch

  #pragma unroll
  for (int p = 0; p < 3; ++p) {
    const float* __restrict__ bias = (p == 0) ? bq : ((p == 1) ? bk : bv);
    f4 acc[4];
    #pragma unroll
    for (int nt = 0; nt < 4; ++nt) acc[nt] = (f4){0.f,0.f,0.f,0.f};
    #pragma unroll
    for (int ks = 0; ks < 4; ++ks)
      #pragma unroll
      for (int nt = 0; nt < 4; ++nt) {
        const h8 wf = *(const h8*)(wlds[p] + (nt*16 + n)*WT_STRIDE + (ks*32 + quad*8)*2);
        acc[nt] = MFMA_K32(xa[ks], wf, acc[nt]);
      }
    #pragma unroll
    for (int nt = 0; nt < 4; ++nt) {
      const float bb = bias[nt*16 + n];
      #pragma unroll
      for (int r = 0; r < 4; ++r) acc[nt][r] += bb;
    }

    if (p == 0) {
      #pragma unroll
      for (int nt = 0; nt < 4; ++nt)
        #pragma unroll
        for (int r = 0; r < 4; ++r) acc[nt][r] *= L2E;
      const int par = lane & 1;
      const unsigned sel = par ? 0x03020706u : 0x05040100u;
      #pragma unroll
      for (int nt = 0; nt < 4; ++nt)
        #pragma unroll
        for (int pp = 0; pp < 2; ++pp) {
          const int r = 2*pp;
          unsigned A  = __builtin_bit_cast(unsigned, pk2(acc[nt][r], acc[nt][r+1]));
          unsigned Bs = (unsigned)__builtin_amdgcn_mov_dpp((int)A, 0xB1, 0xF, 0xF, true);
          unsigned w  = __builtin_amdgcn_perm(Bs, A, sel);
          const int orow = r0 + wv*16 + 4*quad + r + par;
          const int ocol = nt*16 + n - par;
          *(unsigned*)((char*)qf + ((size_t)orow*UDIM + ocol)*2) = w;
        }
    } else if (p == 1) {
      char* base = kbnc + wv*(16*KB_STRIDE);
      #pragma unroll
      for (int nt = 0; nt < 4; ++nt)
        #pragma unroll
        for (int r = 0; r < 4; ++r)
          *(_Float16*)(base + (4*quad + r)*KB_STRIDE + (nt*16 + n)*2) =
              (_Float16)acc[nt][r];
      _Float16* kdst = kswz + (size_t)b*SEQ*UDIM;
      #pragma unroll
      for (int ks = 0; ks < 2; ++ks) {
        const h8 f = *(const h8*)(base + n*KB_STRIDE + ks*64 + quad*16);
        *(h8*)(kdst + ((size_t)(kb*2 + ks)*64 + lane)*8) = f;
      }
    } else {
      // V in K32 A-frag layout.
      _Float16* vdst = vswz + (size_t)b*SEQ*UDIM + (size_t)vt*4096;
      const int hh = wv >> 1;
      const int qp = 2*(wv & 1) + (quad >> 1);
      const int jb = (quad & 1) * 4;
      #pragma unroll
      for (int nt = 0; nt < 4; ++nt) {
        int2 t;
        t.x = __builtin_bit_cast(int, pk2(acc[nt][0], acc[nt][1]));
        t.y = __builtin_bit_cast(int, pk2(acc[nt][2], acc[nt][3]));
        *(int2*)(vdst + (hh*4 + nt)*512 + (16*qp + n)*8 + jb) = t;
      }
    }
  }
}

// ---------------- Kernel B: flash with per-block LDS K/V staging ----------
// R14: all 4 waves of a block previously loaded IDENTICAL K/V tiles into
// registers (16 x 1KB global loads per wave-tile = 192KB/CU-round vs ~64B/cyc
// per-CU VMEM path = 3072 cyc > matrix 2100 cyc -> VMEM-bound, 75% waste).
// Now: tile staged once per block into LDS via global_load_lds (4 instrs/wave),
// double-buffered, one __syncthreads per tile; frags read via ds_read_b128 at
// the same slot*1024+lane*16 offsets. VMEM/CU-round: 192KB -> 48KB.
__global__ __launch_bounds__(256, 3) void flash_attn_t(
    const _Float16* __restrict__ qf, const _Float16* __restrict__ kswz,
    const _Float16* __restrict__ vswz,
    _Float16* __restrict__ opart, float* __restrict__ Mp, float* __restrict__ Lp)
{
  const int qt = blockIdx.x, b = blockIdx.y, sp = blockIdx.z;
  const int ns = gridDim.z;
  const int kt0 = (sp * NT) / ns;
  const int kt1 = ((sp + 1) * NT) / ns;
  const int tid = threadIdx.x;
  const int lane = tid & 63, wid = tid >> 6;
  const int n = lane & 15, quad = lane >> 4;
  const int qbase = qt*128 + wid*32;

  __shared__ __align__(16) char kv[2][16384];   // [dbuf][K 8KB | V 8KB]

  const char* __restrict__ kbase = (const char*)kswz + (size_t)b*SEQ*UDIM*2;
  const char* __restrict__ vbase = (const char*)vswz + (size_t)b*SEQ*UDIM*2;
  const int s0 = wid*2;      // this wave's slot pair
  const int lb = lane*16;

  // ---- prime tile kt0 -> buf0 (async; drained by the first barrier) ----
  {
    const char* kb_ = kbase + (size_t)kt0*8192;
    const char* vb_ = vbase + (size_t)kt0*8192;
    #pragma unroll
    for (int s = 0; s < 2; ++s) {
      stage16(kb_ + (s0+s)*1024 + lb, &kv[0][(s0+s)*1024]);
      stage16(vb_ + (s0+s)*1024 + lb, &kv[0][8192 + (s0+s)*1024]);
    }
  }

  const _Float16* __restrict__ qb = qf + (size_t)b*SEQ*UDIM;
  h8 qB[2][2];
  #pragma unroll
  for (int nt = 0; nt < 2; ++nt)
    #pragma unroll
    for (int ks = 0; ks < 2; ++ks)
      qB[nt][ks] = *(const h8*)(qb + (size_t)(qbase + nt*16 + n)*UDIM + ks*32 + quad*8);

  f4 O[4][2], Ol[2];
  #pragma unroll
  for (int ut = 0; ut < 4; ++ut)
    #pragma unroll
    for (int nt = 0; nt < 2; ++nt) O[ut][nt] = (f4){0.f,0.f,0.f,0.f};
  Ol[0] = (f4){0.f,0.f,0.f,0.f};
  Ol[1] = (f4){0.f,0.f,0.f,0.f};

  float M[2] = {-1e30f, -1e30f};

  h8 ones8;
  { const _Float16 o = (_Float16)1.0f;
    #pragma unroll
    for (int i = 0; i < 8; ++i) ones8[i] = o; }

  // repack gather addresses (bytes): lo from lane 32*(quad&1)+n, hi = +16
  const int alo4 = ((32*((lane >> 4) & 1) + (lane & 15)) << 2);
  const int ahi4 = alo4 + 64;
  const bool qlo = (lane < 32);

  __syncthreads();   // kt0 staging resident

  int cur = 0;
  for (int t = kt0; t < kt1; ++t) {
    // ---- prefetch tile t+1 into the other buffer (async across barrier) ----
    if (t + 1 < kt1) {
      const char* kb_ = kbase + (size_t)(t+1)*8192;
      const char* vb_ = vbase + (size_t)(t+1)*8192;
      char* dst = kv[cur ^ 1];
      #pragma unroll
      for (int s = 0; s < 2; ++s) {
        stage16(kb_ + (s0+s)*1024 + lb, dst + (s0+s)*1024);
        stage16(vb_ + (s0+s)*1024 + lb, dst + 8192 + (s0+s)*1024);
      }
    }

    const char* Kl = kv[cur] + lb;
    const char* Vl = Kl + 8192;

    // ---- K frags from LDS ----
    h8 ka[4][2];
    #pragma unroll
    for (int mt = 0; mt < 4; ++mt)
      #pragma unroll
      for (int ks = 0; ks < 2; ++ks)
        ka[mt][ks] = *(const h8*)(Kl + (mt*2 + ks)*1024);

    // ---- S^T = K·Q^T (log2 domain: q pre-scaled) ----
    f4 S[4][2];
    #pragma unroll
    for (int mt = 0; mt < 4; ++mt)
      #pragma unroll
      for (int nt = 0; nt < 2; ++nt) S[mt][nt] = (f4){0.f,0.f,0.f,0.f};
    #pragma unroll
    for (int ks = 0; ks < 2; ++ks)
      #pragma unroll
      for (int mt = 0; mt < 4; ++mt)
        #pragma unroll
        for (int nt = 0; nt < 2; ++nt)
          S[mt][nt] = MFMA_K32(ka[mt][ks], qB[nt][ks], S[mt][nt]);

    // ---- row max: tree + 2 shuffles ----
    float mn[2];
    #pragma unroll
    for (int nt = 0; nt < 2; ++nt) {
      float m0 = fmaxf(fmaxf(S[0][nt][0], S[0][nt][1]), fmaxf(S[0][nt][2], S[0][nt][3]));
      float m1 = fmaxf(fmaxf(S[1][nt][0], S[1][nt][1]), fmaxf(S[1][nt][2], S[1][nt][3]));
      float m2 = fmaxf(fmaxf(S[2][nt][0], S[2][nt][1]), fmaxf(S[2][nt][2], S[2][nt][3]));
      float m3 = fmaxf(fmaxf(S[3][nt][0], S[3][nt][1]), fmaxf(S[3][nt][2], S[3][nt][3]));
      float rm = fmaxf(fmaxf(m0, m1), fmaxf(m2, m3));
      rm = fmaxf(rm, __shfl_xor(rm, 16));
      rm = fmaxf(rm, __shfl_xor(rm, 32));
      mn[nt] = fmaxf(M[nt], rm);
    }

    // ---- rescale O only if some lane's max moved ----
    const bool nochange = (mn[0] == M[0]) && (mn[1] == M[1]);
    if (!__all(nochange)) {
      #pragma unroll
      for (int nt = 0; nt < 2; ++nt) {
        const float alpha = fexp2(M[nt] - mn[nt]);
        #pragma unroll
        for (int ut = 0; ut < 4; ++ut)
          #pragma unroll
          for (int r = 0; r < 4; ++r) O[ut][nt][r] *= alpha;
        #pragma unroll
        for (int r = 0; r < 4; ++r) Ol[nt][r] *= alpha;
      }
    }
    M[0] = mn[0]; M[1] = mn[1];

    // ---- P = exp2(S - m); pack to h4 (QK C-layout) ----
    h4 pB[4][2];
    #pragma unroll
    for (int mt = 0; mt < 4; ++mt)
      #pragma unroll
      for (int nt = 0; nt < 2; ++nt) {
        #pragma unroll
        for (int r = 0; r < 4; ++r)
          S[mt][nt][r] = fexp2(S[mt][nt][r] - mn[nt]);
        int2 tt;
        tt.x = __builtin_bit_cast(int, pk2(S[mt][nt][0], S[mt][nt][1]));
        tt.y = __builtin_bit_cast(int, pk2(S[mt][nt][2], S[mt][nt][3]));
        pB[mt][nt] = __builtin_bit_cast(h4, tt);
      }

    // ---- repack hh=0 (keys 0..31): pB[0],pB[1] -> K32 B-frags ----
    h8 pb32a[2];
    #pragma unroll
    for (int nt = 0; nt < 2; ++nt) {
      const int2 X = __builtin_bit_cast(int2, pB[0][nt]);
      const int2 Y = __builtin_bit_cast(int2, pB[1][nt]);
      int4 o;
      { int a0 = __builtin_amdgcn_ds_bpermute(alo4, X.x);
        int b0 = __builtin_amdgcn_ds_bpermute(alo4, Y.x);
        int a1 = __builtin_amdgcn_ds_bpermute(alo4, X.y);
        int b1 = __builtin_amdgcn_ds_bpermute(alo4, Y.y);
        int a2 = __builtin_amdgcn_ds_bpermute(ahi4, X.x);
        int b2 = __builtin_amdgcn_ds_bpermute(ahi4, Y.x);
        int a3 = __builtin_amdgcn_ds_bpermute(ahi4, X.y);
        int b3 = __builtin_amdgcn_ds_bpermute(ahi4, Y.y);
        o.x = qlo ? a0 : b0; o.y = qlo ? a1 : b1;
        o.z = qlo ? a2 : b2; o.w = qlo ? a3 : b3; }
      pb32a[nt] = __builtin_bit_cast(h8, o);
    }

    // ---- V hh=0 frags from LDS ----
    h8 va0[4];
    #pragma unroll
    for (int ut = 0; ut < 4; ++ut) va0[ut] = *(const h8*)(Vl + ut*1024);

    // ---- PV hh=0 ----
    #pragma unroll
    for (int ut = 0; ut < 4; ++ut)
      #pragma unroll
      for (int nt = 0; nt < 2; ++nt)
        O[ut][nt] = MFMA_K32(va0[ut], pb32a[nt], O[ut][nt]);
    #pragma unroll
    for (int nt = 0; nt < 2; ++nt)
      Ol[nt] = MFMA_K32(ones8, pb32a[nt], Ol[nt]);

    // ---- repack hh=1 (keys 32..63): pB[2],pB[3] ----
    h8 pb32b[2];
    #pragma unroll
    for (int nt = 0; nt < 2; ++nt) {
      const int2 X = __builtin_bit_cast(int2, pB[2][nt]);
      const int2 Y = __builtin_bit_cast(int2, pB[3][nt]);
      int4 o;
      { int a0 = __builtin_amdgcn_ds_bpermute(alo4, X.x);
        int b0 = __builtin_amdgcn_ds_bpermute(alo4, Y.x);
        int a1 = __builtin_amdgcn_ds_bpermute(alo4, X.y);
        int b1 = __builtin_amdgcn_ds_bpermute(alo4, Y.y);
        int a2 = __builtin_amdgcn_ds_bpermute(ahi4, X.x);
        int b2 = __builtin_amdgcn_ds_bpermute(ahi4, Y.x);
        int a3 = __builtin_amdgcn_ds_bpermute(ahi4, X.y);
        int b3 = __builtin_amdgcn_ds_bpermute(ahi4, Y.y);
        o.x = qlo ? a0 : b0; o.y = qlo ? a1 : b1;
        o.z = qlo ? a2 : b2; o.w = qlo ? a3 : b3; }
      pb32b[nt] = __builtin_bit_cast(h8, o);
    }

    // ---- V hh=1 frags from LDS ----
    h8 va1[4];
    #pragma unroll
    for (int ut = 0; ut < 4; ++ut) va1[ut] = *(const h8*)(Vl + (4 + ut)*1024);

    // ---- PV hh=1 ----
    #pragma unroll
    for (int ut = 0; ut < 4; ++ut)
      #pragma unroll
      for (int nt = 0; nt < 2; ++nt)
        O[ut][nt] = MFMA_K32(va1[ut], pb32b[nt], O[ut][nt]);
    #pragma unroll
    for (int nt = 0; nt < 2; ++nt)
      Ol[nt] = MFMA_K32(ones8, pb32b[nt], Ol[nt]);

    // barrier: (a) drains vmcnt -> t+1 staged; (b) all waves done with kv[cur]
    if (t + 1 < kt1) __syncthreads();
    cur ^= 1;
  }

  // ---- epilogue ----
  const size_t rowg = (size_t)sp*BS + (size_t)b*SEQ + qbase;
  #pragma unroll
  for (int nt = 0; nt < 2; ++nt) {
    char* __restrict__ orow = (char*)(opart + (rowg + nt*16 + n)*UDIM);
    #pragma unroll
    for (int ut = 0; ut < 4; ++ut)
      #pragma unroll
      for (int p = 0; p < 2; ++p)
        *(unsigned*)(orow + (ut*16 + quad*4 + 2*p)*2) =
            __builtin_bit_cast(unsigned, pk2(O[ut][nt][2*p], O[ut][nt][2*p+1]));
    if (quad == 0) {
      Mp[rowg + nt*16 + n] = M[nt];        // log2 domain
      Lp[rowg + nt*16 + n] = Ol[nt][0];
    }
  }
}

// ---------------- Kernel C: merge key-split partials ----------------
__global__ __launch_bounds__(256) void merge_out(
    const _Float16* __restrict__ opart, const float* __restrict__ Mp,
    const float* __restrict__ Lp, float* __restrict__ out, int nsplit)
{
  const int tid = threadIdx.x;
  const int row = blockIdx.x*16 + (tid >> 4);
  const int u4  = (tid & 15) * 4;
  float M = -1e30f;
  for (int s = 0; s < nsplit; ++s) M = fmaxf(M, Mp[(size_t)s*BS + row]);
  f4 num = (f4){0.f,0.f,0.f,0.f};
  float den = 0.f;
  for (int s = 0; s < nsplit; ++s) {
    const float w = fexp2(Mp[(size_t)s*BS + row] - M);
    den += w * Lp[(size_t)s*BS + row];
    const h4 op = *(const h4*)(opart + ((size_t)s*BS + row)*UDIM + u4);
    #pragma unroll
    for (int i = 0; i < 4; ++i) num[i] += w * (float)op[i];
  }
  const float dinv = 1.f / den;
  *(f4*)(out + (size_t)row*UDIM + u4) = num * dinv;
}

extern "C" void kernel_launch(void* const* d_in, const int* in_sizes, int n_in,
                              void* d_out, int out_size, void* d_ws, size_t ws_size,
                              hipStream_t stream) {
  (void)in_sizes; (void)n_in; (void)out_size;
  const float* x  = (const float*)d_in[0];
  const float* Wq = (const float*)d_in[1];
  const float* bq = (const float*)d_in[2];
  const float* Wk = (const float*)d_in[3];
  const float* bk = (const float*)d_in[4];
  const float* Wv = (const float*)d_in[5];
  const float* bv = (const float*)d_in[6];
  float* out = (float*)d_out;

  char* ws = (char*)d_ws;
  const size_t fBytes = (size_t)BS * UDIM * 2;
  auto need = [](int nsp) {
    return (size_t)3*BS*UDIM*2 + (size_t)nsp*BS*4*2 + (size_t)nsp*BS*UDIM*2;
  };
  int nsplit;
  if      (ws_size >= need(NSPLIT)) nsplit = NSPLIT;
  else if (ws_size >= need(4))      nsplit = 4;
  else if (ws_size >= need(2))      nsplit = 2;
  else                              nsplit = 1;

  _Float16* qf   = (_Float16*)(ws);
  _Float16* kswz = (_Float16*)(ws + fBytes);
  _Float16* vswz = (_Float16*)(ws + 2*fBytes);
  float* Mp      = (float*)(ws + 3*fBytes);
  float* Lp      = (float*)(ws + 3*fBytes + (size_t)nsplit*BS*4);
  _Float16* opart = (_Float16*)(ws + 3*fBytes + (size_t)nsplit*BS*8);

  proj_mfma<<<dim3(BS/64), 256, 0, stream>>>(x, Wq, bq, Wk, bk, Wv, bv, qf, kswz, vswz);
  flash_attn_t<<<dim3(SEQ/128, BATCH, nsplit), 256, 0, stream>>>(
      qf, kswz, vswz, opart, Mp, Lp);
  merge_out<<<dim3(BS/16), 256, 0, stream>>>(opart, Mp, Lp, out, nsplit);
}